// Round 1
// 3561.189 us; speedup vs baseline: 1.0203x; 1.0203x over previous
//
#include <hip/hip_runtime.h>
#include <cstdint>
#include <cstddef>

typedef unsigned short u16;
typedef unsigned int   u32;

#define B_    2
#define T_    4096
#define HID   2048
#define NH    6
#define DK    256
#define DV    512
#define KD    1536   // NH*DK
#define VD    3072   // NH*DV
#define MROWS 8192   // B_*T_

typedef short short8 __attribute__((ext_vector_type(8)));
typedef float f32x4v __attribute__((ext_vector_type(4)));

__device__ __forceinline__ float bf2f(u16 u){
  union { u32 i; float f; } v; v.i = ((u32)u) << 16; return v.f;
}
__device__ __forceinline__ u16 f2bf(float f){
  union { float f; u32 i; } v; v.f = f;
  u32 r = v.i + 0x7fffu + ((v.i >> 16) & 1u);
  return (u16)(r >> 16);
}
__device__ __forceinline__ u32 pack2(float a, float b){
  return (u32)f2bf(a) | ((u32)f2bf(b) << 16);
}
__device__ __forceinline__ void unpack8(uint4 p, float* f){
  f[0]=bf2f((u16)(p.x&0xffffu)); f[1]=bf2f((u16)(p.x>>16));
  f[2]=bf2f((u16)(p.y&0xffffu)); f[3]=bf2f((u16)(p.y>>16));
  f[4]=bf2f((u16)(p.z&0xffffu)); f[5]=bf2f((u16)(p.z>>16));
  f[6]=bf2f((u16)(p.w&0xffffu)); f[7]=bf2f((u16)(p.w>>16));
}

// ---------------------------------------------------------------------------
// Transpose + downcast: in f32 [R][C] -> out bf16 [C][R]. Grid (C/64, R/64).
// ---------------------------------------------------------------------------
__global__ __launch_bounds__(256)
void transpose_f2b(const float* __restrict__ in, u16* __restrict__ out, int R, int C)
{
  __shared__ u16 tile[64][72];
  int tid = threadIdx.x;
  int lx = tid & 63, ly = tid >> 6;
  int x = blockIdx.x*64 + lx;
  #pragma unroll
  for (int i = 0; i < 64; i += 4)
    tile[i+ly][lx] = f2bf(in[(size_t)(blockIdx.y*64 + i + ly)*C + x]);
  __syncthreads();
  int x2 = blockIdx.y*64 + lx;
  #pragma unroll
  for (int i = 0; i < 64; i += 4)
    out[(size_t)(blockIdx.x*64 + i + ly)*R + x2] = tile[lx][i+ly];
}

// ---------------------------------------------------------------------------
// GEMM variant 1: A bf16, Bt bf16, C bf16 (m97 structure). C[M,N] = A * Bt^T.
// ---------------------------------------------------------------------------
__global__ __launch_bounds__(256)
void gemm_bt(const u16* __restrict__ A, const u16* __restrict__ Bt, u16* __restrict__ C,
             int M, int N, int K)
{
  __shared__ __align__(16) u16 As[128*32];
  __shared__ __align__(16) u16 Bs[128*32];
  const int tid  = threadIdx.x;
  const int wave = tid >> 6;
  const int lane = tid & 63;
  const int bm = blockIdx.y, bn = blockIdx.x;
  const int fr = lane & 15, fq = lane >> 4;
  const int wm = (wave >> 1) * 64, wn = (wave & 1) * 64;
  const int srow = tid >> 2, spart = tid & 3;
  const u16* Abase = A  + (size_t)bm * 128 * K;
  const u16* Bbase = Bt + (size_t)bn * 128 * K;

  f32x4v acc[4][4];
  #pragma unroll
  for (int i=0;i<4;i++)
    #pragma unroll
    for (int j=0;j<4;j++){ f32x4v z = {0.f,0.f,0.f,0.f}; acc[i][j] = z; }

  for (int k0 = 0; k0 < K; k0 += 32){
    #pragma unroll
    for (int c = 0; c < 2; ++c){
      const u16* ga = Abase + (size_t)(c*64 + srow) * K + k0 + spart*8;
      const u16* gb = Bbase + (size_t)(c*64 + srow) * K + k0 + spart*8;
      u16* la = &As[(c*64 + wave*16) * 32];
      u16* lb = &Bs[(c*64 + wave*16) * 32];
      __builtin_amdgcn_global_load_lds((const __attribute__((address_space(1))) void*)ga,
                                       (__attribute__((address_space(3))) void*)la, 16, 0, 0);
      __builtin_amdgcn_global_load_lds((const __attribute__((address_space(1))) void*)gb,
                                       (__attribute__((address_space(3))) void*)lb, 16, 0, 0);
    }
    __syncthreads();
    short8 af[4], bfm[4];
    #pragma unroll
    for (int mi=0;mi<4;mi++) af[mi]  = *(const short8*)&As[(wm + mi*16 + fr)*32 + fq*8];
    #pragma unroll
    for (int ni=0;ni<4;ni++) bfm[ni] = *(const short8*)&Bs[(wn + ni*16 + fr)*32 + fq*8];
    #pragma unroll
    for (int mi=0;mi<4;mi++)
      #pragma unroll
      for (int ni=0;ni<4;ni++)
        acc[mi][ni] = __builtin_amdgcn_mfma_f32_16x16x32_bf16(af[mi], bfm[ni], acc[mi][ni], 0, 0, 0);
    __syncthreads();
  }

  #pragma unroll
  for (int mi=0;mi<4;mi++){
    #pragma unroll
    for (int ni=0;ni<4;ni++){
      int r0 = bm*128 + wm + mi*16 + fq*4;
      int c0 = bn*128 + wn + ni*16 + fr;
      #pragma unroll
      for (int rr=0;rr<4;rr++)
        C[(size_t)(r0+rr)*N + c0] = f2bf(acc[mi][ni][rr]);
    }
  }
}

// ---------------------------------------------------------------------------
// GEMM variant 2: A f32 (cvt to bf16 during LDS staging), Bt bf16, C bf16.
// ---------------------------------------------------------------------------
__global__ __launch_bounds__(256)
void gemm_f32a_bt(const float* __restrict__ A, const u16* __restrict__ Bt, u16* __restrict__ C,
                  int M, int N, int K)
{
  __shared__ __align__(16) u16 As[128*32];
  __shared__ __align__(16) u16 Bs[128*32];
  const int tid  = threadIdx.x;
  const int wave = tid >> 6;
  const int lane = tid & 63;
  const int bm = blockIdx.y, bn = blockIdx.x;
  const int fr = lane & 15, fq = lane >> 4;
  const int wm = (wave >> 1) * 64, wn = (wave & 1) * 64;
  const int srow = tid >> 2, spart = tid & 3;
  const float* Abase = A + (size_t)bm * 128 * K;
  const u16*   Bbase = Bt + (size_t)bn * 128 * K;

  f32x4v acc[4][4];
  #pragma unroll
  for (int i=0;i<4;i++)
    #pragma unroll
    for (int j=0;j<4;j++){ f32x4v z = {0.f,0.f,0.f,0.f}; acc[i][j] = z; }

  for (int k0 = 0; k0 < K; k0 += 32){
    #pragma unroll
    for (int c = 0; c < 2; ++c){
      const u16* gb = Bbase + (size_t)(c*64 + srow) * K + k0 + spart*8;
      u16* lb = &Bs[(c*64 + wave*16) * 32];
      __builtin_amdgcn_global_load_lds((const __attribute__((address_space(1))) void*)gb,
                                       (__attribute__((address_space(3))) void*)lb, 16, 0, 0);
      const float4* ga = (const float4*)(Abase + (size_t)(c*64 + srow) * K + k0 + spart*8);
      float4 v0 = ga[0], v1 = ga[1];
      uint4 pk;
      pk.x = pack2(v0.x, v0.y); pk.y = pack2(v0.z, v0.w);
      pk.z = pack2(v1.x, v1.y); pk.w = pack2(v1.z, v1.w);
      *(uint4*)&As[(c*64 + srow)*32 + spart*8] = pk;
    }
    __syncthreads();
    short8 af[4], bfm[4];
    #pragma unroll
    for (int mi=0;mi<4;mi++) af[mi]  = *(const short8*)&As[(wm + mi*16 + fr)*32 + fq*8];
    #pragma unroll
    for (int ni=0;ni<4;ni++) bfm[ni] = *(const short8*)&Bs[(wn + ni*16 + fr)*32 + fq*8];
    #pragma unroll
    for (int mi=0;mi<4;mi++)
      #pragma unroll
      for (int ni=0;ni<4;ni++)
        acc[mi][ni] = __builtin_amdgcn_mfma_f32_16x16x32_bf16(af[mi], bfm[ni], acc[mi][ni], 0, 0, 0);
    __syncthreads();
  }

  #pragma unroll
  for (int mi=0;mi<4;mi++){
    #pragma unroll
    for (int ni=0;ni<4;ni++){
      int r0 = bm*128 + wm + mi*16 + fq*4;
      int c0 = bn*128 + wn + ni*16 + fr;
      #pragma unroll
      for (int rr=0;rr<4;rr++)
        C[(size_t)(r0+rr)*N + c0] = f2bf(acc[mi][ni][rr]);
    }
  }
}

// ---------------------------------------------------------------------------
// GEMM variant 3: A bf16, Bt bf16, C f32 (final output projection).
// ---------------------------------------------------------------------------
__global__ __launch_bounds__(256)
void gemm_bt_f32out(const u16* __restrict__ A, const u16* __restrict__ Bt, float* __restrict__ C,
                    int M, int N, int K)
{
  __shared__ __align__(16) u16 As[128*32];
  __shared__ __align__(16) u16 Bs[128*32];
  const int tid  = threadIdx.x;
  const int wave = tid >> 6;
  const int lane = tid & 63;
  const int bm = blockIdx.y, bn = blockIdx.x;
  const int fr = lane & 15, fq = lane >> 4;
  const int wm = (wave >> 1) * 64, wn = (wave & 1) * 64;
  const int srow = tid >> 2, spart = tid & 3;
  const u16* Abase = A  + (size_t)bm * 128 * K;
  const u16* Bbase = Bt + (size_t)bn * 128 * K;

  f32x4v acc[4][4];
  #pragma unroll
  for (int i=0;i<4;i++)
    #pragma unroll
    for (int j=0;j<4;j++){ f32x4v z = {0.f,0.f,0.f,0.f}; acc[i][j] = z; }

  for (int k0 = 0; k0 < K; k0 += 32){
    #pragma unroll
    for (int c = 0; c < 2; ++c){
      const u16* ga = Abase + (size_t)(c*64 + srow) * K + k0 + spart*8;
      const u16* gb = Bbase + (size_t)(c*64 + srow) * K + k0 + spart*8;
      u16* la = &As[(c*64 + wave*16) * 32];
      u16* lb = &Bs[(c*64 + wave*16) * 32];
      __builtin_amdgcn_global_load_lds((const __attribute__((address_space(1))) void*)ga,
                                       (__attribute__((address_space(3))) void*)la, 16, 0, 0);
      __builtin_amdgcn_global_load_lds((const __attribute__((address_space(1))) void*)gb,
                                       (__attribute__((address_space(3))) void*)lb, 16, 0, 0);
    }
    __syncthreads();
    short8 af[4], bfm[4];
    #pragma unroll
    for (int mi=0;mi<4;mi++) af[mi]  = *(const short8*)&As[(wm + mi*16 + fr)*32 + fq*8];
    #pragma unroll
    for (int ni=0;ni<4;ni++) bfm[ni] = *(const short8*)&Bs[(wn + ni*16 + fr)*32 + fq*8];
    #pragma unroll
    for (int mi=0;mi<4;mi++)
      #pragma unroll
      for (int ni=0;ni<4;ni++)
        acc[mi][ni] = __builtin_amdgcn_mfma_f32_16x16x32_bf16(af[mi], bfm[ni], acc[mi][ni], 0, 0, 0);
    __syncthreads();
  }

  #pragma unroll
  for (int mi=0;mi<4;mi++){
    #pragma unroll
    for (int ni=0;ni<4;ni++){
      int r0 = bm*128 + wm + mi*16 + fq*4;
      int c0 = bn*128 + wn + ni*16 + fr;
      #pragma unroll
      for (int rr=0;rr<4;rr++)
        C[(size_t)(r0+rr)*N + c0] = acc[mi][ni][rr];
    }
  }
}

// ---------------------------------------------------------------------------
// Wa/Wb projections (N=6) + softplus/sigmoid -> gb = {exp(g_decay), beta}.
// decay pre-exponentiated here so the scan doesn't run v_exp per thread/token.
// ---------------------------------------------------------------------------
__global__ __launch_bounds__(64)
void proj_ab(const float* __restrict__ hs, const float* __restrict__ Wa, const float* __restrict__ Wb,
             const float* __restrict__ A_log, const float* __restrict__ dt_b,
             float2* __restrict__ gb)
{
  int r = blockIdx.x;
  int lane = threadIdx.x;
  float hv[32];
  const float4* hp = (const float4*)(hs + (size_t)r*HID + lane*32);
  #pragma unroll
  for (int q=0;q<8;q++){ float4 v = hp[q]; hv[q*4]=v.x; hv[q*4+1]=v.y; hv[q*4+2]=v.z; hv[q*4+3]=v.w; }
  float a[6] = {0,0,0,0,0,0}, b[6] = {0,0,0,0,0,0};
  {
    const float* wp = Wa + (size_t)lane*192;
    #pragma unroll
    for (int u=0; u<48; ++u){
      float4 wv = *(const float4*)(wp + u*4);
      float wf[4] = {wv.x, wv.y, wv.z, wv.w};
      #pragma unroll
      for (int p=0;p<4;p++){ int idx = u*4+p; a[idx%6] += hv[idx/6] * wf[p]; }
    }
  }
  {
    const float* wp = Wb + (size_t)lane*192;
    #pragma unroll
    for (int u=0; u<48; ++u){
      float4 wv = *(const float4*)(wp + u*4);
      float wf[4] = {wv.x, wv.y, wv.z, wv.w};
      #pragma unroll
      for (int p=0;p<4;p++){ int idx = u*4+p; b[idx%6] += hv[idx/6] * wf[p]; }
    }
  }
  #pragma unroll
  for (int off=1; off<64; off<<=1){
    #pragma unroll
    for (int j=0;j<6;j++){ a[j] += __shfl_xor(a[j], off); b[j] += __shfl_xor(b[j], off); }
  }
  if (lane == 0){
    #pragma unroll
    for (int j=0;j<6;j++){
      float da = a[j] + dt_b[j];
      float sp = (da > 15.f) ? da : log1pf(expf(da));
      float g  = -expf(A_log[j]) * sp;
      float2 o2; o2.x = __expf(g); o2.y = 1.f / (1.f + expf(-b[j]));
      gb[(size_t)r*6 + j] = o2;
    }
  }
}

// ---------------------------------------------------------------------------
// Causal conv(K=4)+SiLU + per-head l2norm (q: scale=1/16, k: 1).
// ---------------------------------------------------------------------------
__global__ __launch_bounds__(256)
void conv_norm_qk(const u16* __restrict__ x, const float* __restrict__ cw,
                  u16* __restrict__ outp, float scale)
{
  int r = blockIdx.x, h = blockIdx.y;
  int t = r & (T_-1);
  int d = threadIdx.x;
  int colg = h*DK + d;
  float4 wv = *(const float4*)(cw + (size_t)colg*4);
  float w[4] = {wv.x, wv.y, wv.z, wv.w};
  float acc = 0.f;
  #pragma unroll
  for (int i=0;i<4;i++){
    int st = t - 3 + i;
    if (st >= 0) acc += bf2f(x[(size_t)(r-3+i)*KD + colg]) * w[i];
  }
  float yv = acc / (1.f + __expf(-acc));
  float ss = yv*yv;
  #pragma unroll
  for (int off=1; off<64; off<<=1) ss += __shfl_xor(ss, off);
  __shared__ float red[4];
  if ((threadIdx.x & 63) == 0) red[threadIdx.x>>6] = ss;
  __syncthreads();
  float tot = red[0]+red[1]+red[2]+red[3];
  float out = yv * rsqrtf(tot) * scale;
  outp[(size_t)r*KD + colg] = f2bf(out);
}

// ---------------------------------------------------------------------------
// Causal conv(K=4)+SiLU for v.
// ---------------------------------------------------------------------------
__global__ __launch_bounds__(384)
void conv_v_k(const u16* __restrict__ x, const float* __restrict__ cw, u16* __restrict__ outp)
{
  int r = blockIdx.x;
  int t = r & (T_-1);
  int c8 = threadIdx.x * 8;
  float w[8][4];
  #pragma unroll
  for (int q=0;q<8;q++){
    float4 wv = *(const float4*)(cw + (size_t)c8*4 + q*4);
    w[q][0]=wv.x; w[q][1]=wv.y; w[q][2]=wv.z; w[q][3]=wv.w;
  }
  float acc[8] = {0,0,0,0,0,0,0,0};
  #pragma unroll
  for (int i=0;i<4;i++){
    int st = t-3+i;
    if (st >= 0){
      uint4 xv = *(const uint4*)(x + (size_t)(r-3+i)*VD + c8);
      float xf[8]; unpack8(xv, xf);
      #pragma unroll
      for (int e=0;e<8;e++) acc[e] += xf[e]*w[e][i];
    }
  }
  u32 pk[4];
  #pragma unroll
  for (int e=0;e<8;e+=2){
    float y0 = acc[e]  /(1.f+__expf(-acc[e]));
    float y1 = acc[e+1]/(1.f+__expf(-acc[e+1]));
    pk[e/2] = pack2(y0, y1);
  }
  uint4 o4; o4.x=pk[0]; o4.y=pk[1]; o4.z=pk[2]; o4.w=pk[3];
  *(uint4*)(outp + (size_t)r*VD + c8) = o4;
}

// ---------------------------------------------------------------------------
// Gated delta rule scan v3 — per-wave serial-latency reduction.
//   * DPP row_ror rotate-add reductions (16-lane rows) — no LDS-pipe ops at
//     all; cuts the pred->delta->S critical chain vs ds_bpermute shuffles.
//   * Unroll x2 with A/B register sets; unconditional pointer-increment
//     prefetch (no per-iteration 64-bit address rebuild, no clamp select).
//     The single one-past-the-end prefetch at t=T_-1 lands in adjacent
//     allocated workspace regions (value discarded).
//   * decay pre-exponentiated + {decay,beta} fused into one float2 load.
//   * 64-thread blocks: grid 1536 = exactly 6 blocks/CU (uniform; removes
//     the 2-vs-1 blocks/CU imbalance of the 384-block version).
// Grid (DV/4, NH, B_) = (128,6,2); block 64 (1 wave = 4 cols x 16 lanes).
// ---------------------------------------------------------------------------
#define ROR_ADD(x, CTRL) \
  x += __int_as_float(__builtin_amdgcn_update_dpp(0, __float_as_int(x), CTRL, 0xf, 0xf, false))
#define REDUCE16(x) do { ROR_ADD(x,0x121); ROR_ADD(x,0x122); ROR_ADD(x,0x124); ROR_ADD(x,0x128); } while(0)

#define SCAN_STEP(CKA,CKB,CQA,CQB,CV,CG, NKA,NKB,NQA,NQB,NV,NG)            \
  do {                                                                      \
    /* issue next-token prefetch first: full iteration of latency cover */  \
    NKA = *(const uint4*)kp; NKB = *(const uint4*)(kp+8);                   \
    NQA = *(const uint4*)qp; NQB = *(const uint4*)(qp+8);                   \
    NV  = *vp; NG = *gp;                                                    \
    kp += KD; qp += KD; vp += VD; gp += NH;                                 \
    float kf[16], qf[16];                                                   \
    unpack8(CKA, kf); unpack8(CKB, kf+8);                                   \
    unpack8(CQA, qf); unpack8(CQB, qf+8);                                   \
    float decay = CG.x, bta = CG.y;                                         \
    float vb = bf2f(CV) * bta;                                              \
    float db = decay * bta;                                                 \
    float p0=0.f,p1=0.f,p2=0.f,p3=0.f;                                      \
    _Pragma("unroll")                                                       \
    for (int i_=0;i_<4;i_++){                                               \
      p0 = fmaf(kf[i_],    S[i_],    p0);                                   \
      p1 = fmaf(kf[i_+4],  S[i_+4],  p1);                                   \
      p2 = fmaf(kf[i_+8],  S[i_+8],  p2);                                   \
      p3 = fmaf(kf[i_+12], S[i_+12], p3);                                   \
    }                                                                       \
    float p = (p0+p1)+(p2+p3);                                              \
    REDUCE16(p);                                                            \
    float delta = fmaf(-db, p, vb);                                         \
    float o0=0.f,o1=0.f,o2=0.f,o3=0.f;                                      \
    _Pragma("unroll")                                                       \
    for (int i_=0;i_<4;i_++){                                               \
      S[i_]    = fmaf(S[i_],    decay, kf[i_]   *delta);                    \
      S[i_+4]  = fmaf(S[i_+4],  decay, kf[i_+4] *delta);                    \
      S[i_+8]  = fmaf(S[i_+8],  decay, kf[i_+8] *delta);                    \
      S[i_+12] = fmaf(S[i_+12], decay, kf[i_+12]*delta);                    \
      o0 = fmaf(qf[i_],    S[i_],    o0);                                   \
      o1 = fmaf(qf[i_+4],  S[i_+4],  o1);                                   \
      o2 = fmaf(qf[i_+8],  S[i_+8],  o2);                                   \
      o3 = fmaf(qf[i_+12], S[i_+12], o3);                                   \
    }                                                                       \
    float oo = (o0+o1)+(o2+o3);                                             \
    REDUCE16(oo);                                                           \
    if (rg == 0) *op = f2bf(oo);                                            \
    op += VD;                                                               \
  } while(0)

__global__ __launch_bounds__(64)
void scan_k3(const u16* __restrict__ qc, const u16* __restrict__ kc, const u16* __restrict__ vc,
             const float2* __restrict__ gb, u16* __restrict__ o)
{
  const int slice = blockIdx.x, h = blockIdx.y, b = blockIdx.z;
  const int tid = threadIdx.x;
  const int col = tid >> 4;            // 0..3
  const int rg  = tid & 15;            // 0..15 (DPP row position)
  const int colg = h*DV + slice*4 + col;
  const size_t rb = (size_t)b * T_;

  const u16*   kp = kc + rb*KD + h*DK + rg*16;
  const u16*   qp = qc + rb*KD + h*DK + rg*16;
  const u16*   vp = vc + rb*VD + colg;
  const float2* gp = gb + rb*NH + h;
  u16*         op = o  + rb*VD + colg;

  float S[16];
  #pragma unroll
  for (int i=0;i<16;i++) S[i] = 0.f;

  // preload token 0 into register set A
  uint4 kaA = *(const uint4*)kp, kbA = *(const uint4*)(kp+8);
  uint4 qaA = *(const uint4*)qp, qbA = *(const uint4*)(qp+8);
  u16 vA = *vp; float2 gA = *gp;
  kp += KD; qp += KD; vp += VD; gp += NH;

  uint4 kaB, kbB, qaB, qbB; u16 vB; float2 gB;

  for (int t = 0; t < T_; t += 2){
    SCAN_STEP(kaA,kbA,qaA,qbA,vA,gA, kaB,kbB,qaB,qbB,vB,gB);
    SCAN_STEP(kaB,kbB,qaB,qbB,vB,gB, kaA,kbA,qaA,qbA,vA,gA);
  }
}

// ---------------------------------------------------------------------------
// RMSNorm(512) * norm_weight(f32) * silu(gate) -> y bf16. Grid (MROWS, NH).
// ---------------------------------------------------------------------------
__global__ __launch_bounds__(256)
void norm_gate_k(const u16* __restrict__ o, const u16* __restrict__ gate,
                 const float* __restrict__ nw, u16* __restrict__ y)
{
  int r = blockIdx.x, h = blockIdx.y;
  size_t base = (size_t)r*VD + h*DV;
  int e = threadIdx.x * 2;
  u32 opair = *(const u32*)(o + base + e);
  float ox = bf2f((u16)(opair & 0xffffu)), oy = bf2f((u16)(opair >> 16));
  float ss = ox*ox + oy*oy;
  #pragma unroll
  for (int off=1; off<64; off<<=1) ss += __shfl_xor(ss, off);
  __shared__ float red[4];
  if ((threadIdx.x & 63) == 0) red[threadIdx.x>>6] = ss;
  __syncthreads();
  float ms = (red[0]+red[1]+red[2]+red[3]) * (1.f/512.f);
  float sc = rsqrtf(ms + 1e-5f);
  u32 gv = *(const u32*)(gate + base + e);
  float g0 = bf2f((u16)(gv & 0xffffu)), g1 = bf2f((u16)(gv >> 16));
  float s0 = g0 / (1.f + __expf(-g0)), s1 = g1 / (1.f + __expf(-g1));
  float y0 = ox * sc * nw[e]   * s0;
  float y1 = oy * sc * nw[e+1] * s1;
  *(u32*)(y + base + e) = pack2(y0, y1);
}

// ---------------------------------------------------------------------------
// Workspace plan (163.9 MB + 4KB pad; regions reused):
//   WT   12.58 MB : transposed+downcast weight (reused 5x, stream-serial)
//   bufA 50.33 MB : q_lin | k_lin  ->  vcp  ->  y
//   bufB 50.33 MB : v_lin          ->  op (bf16)
//   bufC 50.33 MB : qc | kc        ->  gatep
//   gb   0.39 MB  : {exp(g), beta} float2   (+4KB overrun pad for prefetch)
// Scan prefetch overruns (one row past end, value discarded) land in the
// next allocated region: qc->kc, kc->gb, vcp(bufA)->bufB, gb->pad.
// ---------------------------------------------------------------------------
extern "C" void kernel_launch(void* const* d_in, const int* in_sizes, int n_in,
                              void* d_out, int out_size, void* d_ws, size_t ws_size,
                              hipStream_t stream)
{
  const float* hs    = (const float*)d_in[0];
  const float* Wq    = (const float*)d_in[1];
  const float* Wk    = (const float*)d_in[2];
  const float* Wv    = (const float*)d_in[3];
  const float* Wa    = (const float*)d_in[4];
  const float* Wb    = (const float*)d_in[5];
  const float* Wg    = (const float*)d_in[6];
  const float* Wo    = (const float*)d_in[7];
  const float* cwq   = (const float*)d_in[8];
  const float* cwk   = (const float*)d_in[9];
  const float* cwv   = (const float*)d_in[10];
  const float* A_log = (const float*)d_in[11];
  const float* dt_b  = (const float*)d_in[12];
  const float* nw    = (const float*)d_in[13];
  float* out = (float*)d_out;

  char* wsb = (char*)d_ws;
  size_t off = 0;
  auto alloc = [&](size_t bytes)->char* {
    char* p = wsb + off; off += (bytes + 255) & ~(size_t)255; return p;
  };
  u16* WT   = (u16*)alloc((size_t)HID*VD*2);
  u16* bufA = (u16*)alloc((size_t)MROWS*VD*2);
  u16* bufB = (u16*)alloc((size_t)MROWS*VD*2);
  u16* bufC = (u16*)alloc((size_t)MROWS*VD*2);
  float2* gb = (float2*)alloc((size_t)MROWS*NH*8 + 4096);

  u16* q_lin = bufA;
  u16* k_lin = bufA + (size_t)MROWS*KD;
  u16* v_lin = bufB;
  u16* qc    = bufC;
  u16* kc    = bufC + (size_t)MROWS*KD;
  u16* vcp   = bufA;          // after q/k convs consume q_lin/k_lin
  u16* op    = bufB;          // after v conv consumes v_lin
  u16* gatep = bufC;          // after scan consumes qc/kc
  u16* yp    = bufA;          // after scan consumes vcp

  dim3 blk256(256);

  // q projection
  transpose_f2b<<<dim3(KD/64, HID/64), blk256, 0, stream>>>(Wq, WT, HID, KD);
  gemm_f32a_bt<<<dim3(KD/128, MROWS/128), blk256, 0, stream>>>(hs, WT, q_lin, MROWS, KD, HID);
  // k projection
  transpose_f2b<<<dim3(KD/64, HID/64), blk256, 0, stream>>>(Wk, WT, HID, KD);
  gemm_f32a_bt<<<dim3(KD/128, MROWS/128), blk256, 0, stream>>>(hs, WT, k_lin, MROWS, KD, HID);
  // v projection
  transpose_f2b<<<dim3(VD/64, HID/64), blk256, 0, stream>>>(Wv, WT, HID, VD);
  gemm_f32a_bt<<<dim3(VD/128, MROWS/128), blk256, 0, stream>>>(hs, WT, v_lin, MROWS, VD, HID);
  // a/b projections + activations -> {exp(g), beta}
  proj_ab<<<dim3(MROWS), dim3(64), 0, stream>>>(hs, Wa, Wb, A_log, dt_b, gb);

  // convs (+ l2norm for q/k; q also * dk^-0.5). q,k before v (vcp overwrites bufA).
  conv_norm_qk<<<dim3(MROWS, NH), blk256, 0, stream>>>(q_lin, cwq, qc, 0.0625f);
  conv_norm_qk<<<dim3(MROWS, NH), blk256, 0, stream>>>(k_lin, cwk, kc, 1.0f);
  conv_v_k<<<dim3(MROWS), dim3(384), 0, stream>>>(v_lin, cwv, vcp);

  // gated delta rule scan v3 -> op (bf16, overwrites v_lin region)
  scan_k3<<<dim3(DV/4, NH, B_), dim3(64), 0, stream>>>(qc, kc, vcp, gb, op);

  // gate projection (into bufC, now free)
  transpose_f2b<<<dim3(VD/64, HID/64), blk256, 0, stream>>>(Wg, WT, HID, VD);
  gemm_f32a_bt<<<dim3(VD/128, MROWS/128), blk256, 0, stream>>>(hs, WT, gatep, MROWS, VD, HID);

  // RMSNorm * nw * silu(gate) -> y (into bufA, now free)
  norm_gate_k<<<dim3(MROWS, NH), blk256, 0, stream>>>(op, gatep, nw, yp);

  // output projection: out(f32) = y @ Wo  (Wo [VD][HID] -> WoT [HID][VD])
  transpose_f2b<<<dim3(HID/64, VD/64), blk256, 0, stream>>>(Wo, WT, VD, HID);
  gemm_bt_f32out<<<dim3(HID/128, MROWS/128), blk256, 0, stream>>>(yp, WT, out, MROWS, HID, VD);
}

// Round 2
// 3217.523 us; speedup vs baseline: 1.1293x; 1.1068x over previous
//
#include <hip/hip_runtime.h>
#include <cstdint>
#include <cstddef>

typedef unsigned short u16;
typedef unsigned int   u32;

#define B_    2
#define T_    4096
#define HID   2048
#define NH    6
#define DK    256
#define DV    512
#define KD    1536   // NH*DK
#define VD    3072   // NH*DV
#define MROWS 8192   // B_*T_

typedef short short8 __attribute__((ext_vector_type(8)));
typedef float f32x4v __attribute__((ext_vector_type(4)));

__device__ __forceinline__ float bf2f(u16 u){
  union { u32 i; float f; } v; v.i = ((u32)u) << 16; return v.f;
}
__device__ __forceinline__ u16 f2bf(float f){
  union { float f; u32 i; } v; v.f = f;
  u32 r = v.i + 0x7fffu + ((v.i >> 16) & 1u);
  return (u16)(r >> 16);
}
__device__ __forceinline__ u32 pack2(float a, float b){
  return (u32)f2bf(a) | ((u32)f2bf(b) << 16);
}
__device__ __forceinline__ void unpack8(uint4 p, float* f){
  f[0]=bf2f((u16)(p.x&0xffffu)); f[1]=bf2f((u16)(p.x>>16));
  f[2]=bf2f((u16)(p.y&0xffffu)); f[3]=bf2f((u16)(p.y>>16));
  f[4]=bf2f((u16)(p.z&0xffffu)); f[5]=bf2f((u16)(p.z>>16));
  f[6]=bf2f((u16)(p.w&0xffffu)); f[7]=bf2f((u16)(p.w>>16));
}

// ---------------------------------------------------------------------------
// Transpose + downcast: in f32 [R][C] -> out bf16 [C][R]. Grid (C/64, R/64).
// ---------------------------------------------------------------------------
__global__ __launch_bounds__(256)
void transpose_f2b(const float* __restrict__ in, u16* __restrict__ out, int R, int C)
{
  __shared__ u16 tile[64][72];
  int tid = threadIdx.x;
  int lx = tid & 63, ly = tid >> 6;
  int x = blockIdx.x*64 + lx;
  #pragma unroll
  for (int i = 0; i < 64; i += 4)
    tile[i+ly][lx] = f2bf(in[(size_t)(blockIdx.y*64 + i + ly)*C + x]);
  __syncthreads();
  int x2 = blockIdx.y*64 + lx;
  #pragma unroll
  for (int i = 0; i < 64; i += 4)
    out[(size_t)(blockIdx.x*64 + i + ly)*R + x2] = tile[lx][i+ly];
}

// ---------------------------------------------------------------------------
// GEMM variant 1: A bf16, Bt bf16, C bf16 (m97 structure). C[M,N] = A * Bt^T.
// ---------------------------------------------------------------------------
__global__ __launch_bounds__(256)
void gemm_bt(const u16* __restrict__ A, const u16* __restrict__ Bt, u16* __restrict__ C,
             int M, int N, int K)
{
  __shared__ __align__(16) u16 As[128*32];
  __shared__ __align__(16) u16 Bs[128*32];
  const int tid  = threadIdx.x;
  const int wave = tid >> 6;
  const int lane = tid & 63;
  const int bm = blockIdx.y, bn = blockIdx.x;
  const int fr = lane & 15, fq = lane >> 4;
  const int wm = (wave >> 1) * 64, wn = (wave & 1) * 64;
  const int srow = tid >> 2, spart = tid & 3;
  const u16* Abase = A  + (size_t)bm * 128 * K;
  const u16* Bbase = Bt + (size_t)bn * 128 * K;

  f32x4v acc[4][4];
  #pragma unroll
  for (int i=0;i<4;i++)
    #pragma unroll
    for (int j=0;j<4;j++){ f32x4v z = {0.f,0.f,0.f,0.f}; acc[i][j] = z; }

  for (int k0 = 0; k0 < K; k0 += 32){
    #pragma unroll
    for (int c = 0; c < 2; ++c){
      const u16* ga = Abase + (size_t)(c*64 + srow) * K + k0 + spart*8;
      const u16* gb = Bbase + (size_t)(c*64 + srow) * K + k0 + spart*8;
      u16* la = &As[(c*64 + wave*16) * 32];
      u16* lb = &Bs[(c*64 + wave*16) * 32];
      __builtin_amdgcn_global_load_lds((const __attribute__((address_space(1))) void*)ga,
                                       (__attribute__((address_space(3))) void*)la, 16, 0, 0);
      __builtin_amdgcn_global_load_lds((const __attribute__((address_space(1))) void*)gb,
                                       (__attribute__((address_space(3))) void*)lb, 16, 0, 0);
    }
    __syncthreads();
    short8 af[4], bfm[4];
    #pragma unroll
    for (int mi=0;mi<4;mi++) af[mi]  = *(const short8*)&As[(wm + mi*16 + fr)*32 + fq*8];
    #pragma unroll
    for (int ni=0;ni<4;ni++) bfm[ni] = *(const short8*)&Bs[(wn + ni*16 + fr)*32 + fq*8];
    #pragma unroll
    for (int mi=0;mi<4;mi++)
      #pragma unroll
      for (int ni=0;ni<4;ni++)
        acc[mi][ni] = __builtin_amdgcn_mfma_f32_16x16x32_bf16(af[mi], bfm[ni], acc[mi][ni], 0, 0, 0);
    __syncthreads();
  }

  #pragma unroll
  for (int mi=0;mi<4;mi++){
    #pragma unroll
    for (int ni=0;ni<4;ni++){
      int r0 = bm*128 + wm + mi*16 + fq*4;
      int c0 = bn*128 + wn + ni*16 + fr;
      #pragma unroll
      for (int rr=0;rr<4;rr++)
        C[(size_t)(r0+rr)*N + c0] = f2bf(acc[mi][ni][rr]);
    }
  }
}

// ---------------------------------------------------------------------------
// GEMM variant 2: A f32 (cvt to bf16 during LDS staging), Bt bf16, C bf16.
// ---------------------------------------------------------------------------
__global__ __launch_bounds__(256)
void gemm_f32a_bt(const float* __restrict__ A, const u16* __restrict__ Bt, u16* __restrict__ C,
                  int M, int N, int K)
{
  __shared__ __align__(16) u16 As[128*32];
  __shared__ __align__(16) u16 Bs[128*32];
  const int tid  = threadIdx.x;
  const int wave = tid >> 6;
  const int lane = tid & 63;
  const int bm = blockIdx.y, bn = blockIdx.x;
  const int fr = lane & 15, fq = lane >> 4;
  const int wm = (wave >> 1) * 64, wn = (wave & 1) * 64;
  const int srow = tid >> 2, spart = tid & 3;
  const float* Abase = A + (size_t)bm * 128 * K;
  const u16*   Bbase = Bt + (size_t)bn * 128 * K;

  f32x4v acc[4][4];
  #pragma unroll
  for (int i=0;i<4;i++)
    #pragma unroll
    for (int j=0;j<4;j++){ f32x4v z = {0.f,0.f,0.f,0.f}; acc[i][j] = z; }

  for (int k0 = 0; k0 < K; k0 += 32){
    #pragma unroll
    for (int c = 0; c < 2; ++c){
      const u16* gb = Bbase + (size_t)(c*64 + srow) * K + k0 + spart*8;
      u16* lb = &Bs[(c*64 + wave*16) * 32];
      __builtin_amdgcn_global_load_lds((const __attribute__((address_space(1))) void*)gb,
                                       (__attribute__((address_space(3))) void*)lb, 16, 0, 0);
      const float4* ga = (const float4*)(Abase + (size_t)(c*64 + srow) * K + k0 + spart*8);
      float4 v0 = ga[0], v1 = ga[1];
      uint4 pk;
      pk.x = pack2(v0.x, v0.y); pk.y = pack2(v0.z, v0.w);
      pk.z = pack2(v1.x, v1.y); pk.w = pack2(v1.z, v1.w);
      *(uint4*)&As[(c*64 + srow)*32 + spart*8] = pk;
    }
    __syncthreads();
    short8 af[4], bfm[4];
    #pragma unroll
    for (int mi=0;mi<4;mi++) af[mi]  = *(const short8*)&As[(wm + mi*16 + fr)*32 + fq*8];
    #pragma unroll
    for (int ni=0;ni<4;ni++) bfm[ni] = *(const short8*)&Bs[(wn + ni*16 + fr)*32 + fq*8];
    #pragma unroll
    for (int mi=0;mi<4;mi++)
      #pragma unroll
      for (int ni=0;ni<4;ni++)
        acc[mi][ni] = __builtin_amdgcn_mfma_f32_16x16x32_bf16(af[mi], bfm[ni], acc[mi][ni], 0, 0, 0);
    __syncthreads();
  }

  #pragma unroll
  for (int mi=0;mi<4;mi++){
    #pragma unroll
    for (int ni=0;ni<4;ni++){
      int r0 = bm*128 + wm + mi*16 + fq*4;
      int c0 = bn*128 + wn + ni*16 + fr;
      #pragma unroll
      for (int rr=0;rr<4;rr++)
        C[(size_t)(r0+rr)*N + c0] = f2bf(acc[mi][ni][rr]);
    }
  }
}

// ---------------------------------------------------------------------------
// GEMM variant 3: A bf16, Bt bf16, C f32 (final output projection).
// ---------------------------------------------------------------------------
__global__ __launch_bounds__(256)
void gemm_bt_f32out(const u16* __restrict__ A, const u16* __restrict__ Bt, float* __restrict__ C,
                    int M, int N, int K)
{
  __shared__ __align__(16) u16 As[128*32];
  __shared__ __align__(16) u16 Bs[128*32];
  const int tid  = threadIdx.x;
  const int wave = tid >> 6;
  const int lane = tid & 63;
  const int bm = blockIdx.y, bn = blockIdx.x;
  const int fr = lane & 15, fq = lane >> 4;
  const int wm = (wave >> 1) * 64, wn = (wave & 1) * 64;
  const int srow = tid >> 2, spart = tid & 3;
  const u16* Abase = A  + (size_t)bm * 128 * K;
  const u16* Bbase = Bt + (size_t)bn * 128 * K;

  f32x4v acc[4][4];
  #pragma unroll
  for (int i=0;i<4;i++)
    #pragma unroll
    for (int j=0;j<4;j++){ f32x4v z = {0.f,0.f,0.f,0.f}; acc[i][j] = z; }

  for (int k0 = 0; k0 < K; k0 += 32){
    #pragma unroll
    for (int c = 0; c < 2; ++c){
      const u16* ga = Abase + (size_t)(c*64 + srow) * K + k0 + spart*8;
      const u16* gb = Bbase + (size_t)(c*64 + srow) * K + k0 + spart*8;
      u16* la = &As[(c*64 + wave*16) * 32];
      u16* lb = &Bs[(c*64 + wave*16) * 32];
      __builtin_amdgcn_global_load_lds((const __attribute__((address_space(1))) void*)ga,
                                       (__attribute__((address_space(3))) void*)la, 16, 0, 0);
      __builtin_amdgcn_global_load_lds((const __attribute__((address_space(1))) void*)gb,
                                       (__attribute__((address_space(3))) void*)lb, 16, 0, 0);
    }
    __syncthreads();
    short8 af[4], bfm[4];
    #pragma unroll
    for (int mi=0;mi<4;mi++) af[mi]  = *(const short8*)&As[(wm + mi*16 + fr)*32 + fq*8];
    #pragma unroll
    for (int ni=0;ni<4;ni++) bfm[ni] = *(const short8*)&Bs[(wn + ni*16 + fr)*32 + fq*8];
    #pragma unroll
    for (int mi=0;mi<4;mi++)
      #pragma unroll
      for (int ni=0;ni<4;ni++)
        acc[mi][ni] = __builtin_amdgcn_mfma_f32_16x16x32_bf16(af[mi], bfm[ni], acc[mi][ni], 0, 0, 0);
    __syncthreads();
  }

  #pragma unroll
  for (int mi=0;mi<4;mi++){
    #pragma unroll
    for (int ni=0;ni<4;ni++){
      int r0 = bm*128 + wm + mi*16 + fq*4;
      int c0 = bn*128 + wn + ni*16 + fr;
      #pragma unroll
      for (int rr=0;rr<4;rr++)
        C[(size_t)(r0+rr)*N + c0] = acc[mi][ni][rr];
    }
  }
}

// ---------------------------------------------------------------------------
// Wa/Wb projections (N=6) + softplus/sigmoid -> gb = {exp(g_decay), beta}.
// ---------------------------------------------------------------------------
__global__ __launch_bounds__(64)
void proj_ab(const float* __restrict__ hs, const float* __restrict__ Wa, const float* __restrict__ Wb,
             const float* __restrict__ A_log, const float* __restrict__ dt_b,
             float2* __restrict__ gb)
{
  int r = blockIdx.x;
  int lane = threadIdx.x;
  float hv[32];
  const float4* hp = (const float4*)(hs + (size_t)r*HID + lane*32);
  #pragma unroll
  for (int q=0;q<8;q++){ float4 v = hp[q]; hv[q*4]=v.x; hv[q*4+1]=v.y; hv[q*4+2]=v.z; hv[q*4+3]=v.w; }
  float a[6] = {0,0,0,0,0,0}, b[6] = {0,0,0,0,0,0};
  {
    const float* wp = Wa + (size_t)lane*192;
    #pragma unroll
    for (int u=0; u<48; ++u){
      float4 wv = *(const float4*)(wp + u*4);
      float wf[4] = {wv.x, wv.y, wv.z, wv.w};
      #pragma unroll
      for (int p=0;p<4;p++){ int idx = u*4+p; a[idx%6] += hv[idx/6] * wf[p]; }
    }
  }
  {
    const float* wp = Wb + (size_t)lane*192;
    #pragma unroll
    for (int u=0; u<48; ++u){
      float4 wv = *(const float4*)(wp + u*4);
      float wf[4] = {wv.x, wv.y, wv.z, wv.w};
      #pragma unroll
      for (int p=0;p<4;p++){ int idx = u*4+p; b[idx%6] += hv[idx/6] * wf[p]; }
    }
  }
  #pragma unroll
  for (int off=1; off<64; off<<=1){
    #pragma unroll
    for (int j=0;j<6;j++){ a[j] += __shfl_xor(a[j], off); b[j] += __shfl_xor(b[j], off); }
  }
  if (lane == 0){
    #pragma unroll
    for (int j=0;j<6;j++){
      float da = a[j] + dt_b[j];
      float sp = (da > 15.f) ? da : log1pf(expf(da));
      float g  = -expf(A_log[j]) * sp;
      float2 o2; o2.x = __expf(g); o2.y = 1.f / (1.f + expf(-b[j]));
      gb[(size_t)r*6 + j] = o2;
    }
  }
}

// ---------------------------------------------------------------------------
// Causal conv(K=4)+SiLU + per-head l2norm (q: scale=1/16, k: 1).
// ---------------------------------------------------------------------------
__global__ __launch_bounds__(256)
void conv_norm_qk(const u16* __restrict__ x, const float* __restrict__ cw,
                  u16* __restrict__ outp, float scale)
{
  int r = blockIdx.x, h = blockIdx.y;
  int t = r & (T_-1);
  int d = threadIdx.x;
  int colg = h*DK + d;
  float4 wv = *(const float4*)(cw + (size_t)colg*4);
  float w[4] = {wv.x, wv.y, wv.z, wv.w};
  float acc = 0.f;
  #pragma unroll
  for (int i=0;i<4;i++){
    int st = t - 3 + i;
    if (st >= 0) acc += bf2f(x[(size_t)(r-3+i)*KD + colg]) * w[i];
  }
  float yv = acc / (1.f + __expf(-acc));
  float ss = yv*yv;
  #pragma unroll
  for (int off=1; off<64; off<<=1) ss += __shfl_xor(ss, off);
  __shared__ float red[4];
  if ((threadIdx.x & 63) == 0) red[threadIdx.x>>6] = ss;
  __syncthreads();
  float tot = red[0]+red[1]+red[2]+red[3];
  float out = yv * rsqrtf(tot) * scale;
  outp[(size_t)r*KD + colg] = f2bf(out);
}

// ---------------------------------------------------------------------------
// Causal conv(K=4)+SiLU for v.
// ---------------------------------------------------------------------------
__global__ __launch_bounds__(384)
void conv_v_k(const u16* __restrict__ x, const float* __restrict__ cw, u16* __restrict__ outp)
{
  int r = blockIdx.x;
  int t = r & (T_-1);
  int c8 = threadIdx.x * 8;
  float w[8][4];
  #pragma unroll
  for (int q=0;q<8;q++){
    float4 wv = *(const float4*)(cw + (size_t)c8*4 + q*4);
    w[q][0]=wv.x; w[q][1]=wv.y; w[q][2]=wv.z; w[q][3]=wv.w;
  }
  float acc[8] = {0,0,0,0,0,0,0,0};
  #pragma unroll
  for (int i=0;i<4;i++){
    int st = t-3+i;
    if (st >= 0){
      uint4 xv = *(const uint4*)(x + (size_t)(r-3+i)*VD + c8);
      float xf[8]; unpack8(xv, xf);
      #pragma unroll
      for (int e=0;e<8;e++) acc[e] += xf[e]*w[e][i];
    }
  }
  u32 pk[4];
  #pragma unroll
  for (int e=0;e<8;e+=2){
    float y0 = acc[e]  /(1.f+__expf(-acc[e]));
    float y1 = acc[e+1]/(1.f+__expf(-acc[e+1]));
    pk[e/2] = pack2(y0, y1);
  }
  uint4 o4; o4.x=pk[0]; o4.y=pk[1]; o4.z=pk[2]; o4.w=pk[3];
  *(uint4*)(outp + (size_t)r*VD + c8) = o4;
}

// ---------------------------------------------------------------------------
// Gated delta rule scan v4 — force the prefetch to survive codegen.
// Round-1 post-mortem: VGPR_Count=40 proved the compiler sank the "prefetch"
// loads to their use sites (40 regs can't hold 2 in-flight sets + S + floats)
// -> every token paid full memory latency (per-token 1447 cy, ~70% stall).
// v4: (a) unpack current set to floats FIRST, then re-issue the SAME set's
// registers with token t+2's loads => load->use distance ~1.7 tokens with
// only 2 register sets; (b) __builtin_amdgcn_sched_barrier(0) after the load
// block pins the 6 loads before the compute so the scheduler cannot sink
// them. Expect VGPR ~90-110 (the proof), per-token ~550-700 cy.
// Grid (DV/4, NH, B_) = (128,6,2); block 64 (1 wave = 4 cols x 16 lanes).
// ---------------------------------------------------------------------------
#define ROR_ADD(x, CTRL) \
  x += __int_as_float(__builtin_amdgcn_update_dpp(0, __float_as_int(x), CTRL, 0xf, 0xf, false))
#define REDUCE16(x) do { ROR_ADD(x,0x121); ROR_ADD(x,0x122); ROR_ADD(x,0x124); ROR_ADD(x,0x128); } while(0)

#define SCAN_STEP4(KA,KB,QA,QB,VV,GG)                                      \
  do {                                                                      \
    /* phase 1: consume current regs (vmcnt waits only for this set) */     \
    float kf[16], qf[16];                                                   \
    unpack8(KA, kf); unpack8(KB, kf+8);                                     \
    unpack8(QA, qf); unpack8(QB, qf+8);                                     \
    float decay = GG.x, bta = GG.y;                                         \
    float vb = bf2f(VV) * bta;                                              \
    float db = decay * bta;                                                 \
    __builtin_amdgcn_sched_barrier(0);                                      \
    /* phase 2: re-issue this set with token t+2 (distance-2 prefetch) */   \
    KA = *(const uint4*)kp; KB = *(const uint4*)(kp+8);                     \
    QA = *(const uint4*)qp; QB = *(const uint4*)(qp+8);                     \
    VV = *vp; GG = *gp;                                                     \
    kp += KD; qp += KD; vp += VD; gp += NH;                                 \
    __builtin_amdgcn_sched_barrier(0);                                      \
    /* phase 3: compute (loads fly during this + all of next step) */       \
    float p0=0.f,p1=0.f,p2=0.f,p3=0.f;                                      \
    _Pragma("unroll")                                                       \
    for (int i_=0;i_<4;i_++){                                               \
      p0 = fmaf(kf[i_],    S[i_],    p0);                                   \
      p1 = fmaf(kf[i_+4],  S[i_+4],  p1);                                   \
      p2 = fmaf(kf[i_+8],  S[i_+8],  p2);                                   \
      p3 = fmaf(kf[i_+12], S[i_+12], p3);                                   \
    }                                                                       \
    float p = (p0+p1)+(p2+p3);                                              \
    REDUCE16(p);                                                            \
    float delta = fmaf(-db, p, vb);                                         \
    float o0=0.f,o1=0.f,o2=0.f,o3=0.f;                                      \
    _Pragma("unroll")                                                       \
    for (int i_=0;i_<4;i_++){                                               \
      S[i_]    = fmaf(S[i_],    decay, kf[i_]   *delta);                    \
      S[i_+4]  = fmaf(S[i_+4],  decay, kf[i_+4] *delta);                    \
      S[i_+8]  = fmaf(S[i_+8],  decay, kf[i_+8] *delta);                    \
      S[i_+12] = fmaf(S[i_+12], decay, kf[i_+12]*delta);                    \
      o0 = fmaf(qf[i_],    S[i_],    o0);                                   \
      o1 = fmaf(qf[i_+4],  S[i_+4],  o1);                                   \
      o2 = fmaf(qf[i_+8],  S[i_+8],  o2);                                   \
      o3 = fmaf(qf[i_+12], S[i_+12], o3);                                   \
    }                                                                       \
    float oo = (o0+o1)+(o2+o3);                                             \
    REDUCE16(oo);                                                           \
    if (rg == 0) *op = f2bf(oo);                                            \
    op += VD;                                                               \
  } while(0)

__global__ __launch_bounds__(64)
void scan_k4(const u16* __restrict__ qc, const u16* __restrict__ kc, const u16* __restrict__ vc,
             const float2* __restrict__ gb, u16* __restrict__ o)
{
  const int slice = blockIdx.x, h = blockIdx.y, b = blockIdx.z;
  const int tid = threadIdx.x;
  const int col = tid >> 4;            // 0..3
  const int rg  = tid & 15;            // 0..15 (DPP row position)
  const int colg = h*DV + slice*4 + col;
  const size_t rb = (size_t)b * T_;

  const u16*   kp = kc + rb*KD + h*DK + rg*16;
  const u16*   qp = qc + rb*KD + h*DK + rg*16;
  const u16*   vp = vc + rb*VD + colg;
  const float2* gp = gb + rb*NH + h;
  u16*         op = o  + rb*VD + colg;

  float S[16];
  #pragma unroll
  for (int i=0;i<16;i++) S[i] = 0.f;

  // preload token 0 -> set A, token 1 -> set B; pointers then at token 2
  uint4 kaA = *(const uint4*)kp, kbA = *(const uint4*)(kp+8);
  uint4 qaA = *(const uint4*)qp, qbA = *(const uint4*)(qp+8);
  u16 vA = *vp; float2 gA = *gp;
  kp += KD; qp += KD; vp += VD; gp += NH;
  uint4 kaB = *(const uint4*)kp, kbB = *(const uint4*)(kp+8);
  uint4 qaB = *(const uint4*)qp, qbB = *(const uint4*)(qp+8);
  u16 vB = *vp; float2 gB = *gp;
  kp += KD; qp += KD; vp += VD; gp += NH;

  for (int t = 0; t < T_; t += 2){
    SCAN_STEP4(kaA,kbA,qaA,qbA,vA,gA);   // token t   (prefetches t+2 -> A)
    SCAN_STEP4(kaB,kbB,qaB,qbB,vB,gB);   // token t+1 (prefetches t+3 -> B)
  }
  // final-iteration prefetch overruns (tokens T_, T_+1) read 2 rows past each
  // stream: qc->kc, kc->gb region, vcp->bufB, gb->its 4KB pad. All inside ws;
  // values discarded.
}

// ---------------------------------------------------------------------------
// RMSNorm(512) * norm_weight(f32) * silu(gate) -> y bf16. Grid (MROWS, NH).
// ---------------------------------------------------------------------------
__global__ __launch_bounds__(256)
void norm_gate_k(const u16* __restrict__ o, const u16* __restrict__ gate,
                 const float* __restrict__ nw, u16* __restrict__ y)
{
  int r = blockIdx.x, h = blockIdx.y;
  size_t base = (size_t)r*VD + h*DV;
  int e = threadIdx.x * 2;
  u32 opair = *(const u32*)(o + base + e);
  float ox = bf2f((u16)(opair & 0xffffu)), oy = bf2f((u16)(opair >> 16));
  float ss = ox*ox + oy*oy;
  #pragma unroll
  for (int off=1; off<64; off<<=1) ss += __shfl_xor(ss, off);
  __shared__ float red[4];
  if ((threadIdx.x & 63) == 0) red[threadIdx.x>>6] = ss;
  __syncthreads();
  float ms = (red[0]+red[1]+red[2]+red[3]) * (1.f/512.f);
  float sc = rsqrtf(ms + 1e-5f);
  u32 gv = *(const u32*)(gate + base + e);
  float g0 = bf2f((u16)(gv & 0xffffu)), g1 = bf2f((u16)(gv >> 16));
  float s0 = g0 / (1.f + __expf(-g0)), s1 = g1 / (1.f + __expf(-g1));
  float y0 = ox * sc * nw[e]   * s0;
  float y1 = oy * sc * nw[e+1] * s1;
  *(u32*)(y + base + e) = pack2(y0, y1);
}

// ---------------------------------------------------------------------------
// Workspace plan (163.9 MB + 4KB pad; regions reused):
//   WT   12.58 MB : transposed+downcast weight (reused 5x, stream-serial)
//   bufA 50.33 MB : q_lin | k_lin  ->  vcp  ->  y
//   bufB 50.33 MB : v_lin          ->  op (bf16)
//   bufC 50.33 MB : qc | kc        ->  gatep
//   gb   0.39 MB  : {exp(g), beta} float2   (+4KB overrun pad for prefetch)
// ---------------------------------------------------------------------------
extern "C" void kernel_launch(void* const* d_in, const int* in_sizes, int n_in,
                              void* d_out, int out_size, void* d_ws, size_t ws_size,
                              hipStream_t stream)
{
  const float* hs    = (const float*)d_in[0];
  const float* Wq    = (const float*)d_in[1];
  const float* Wk    = (const float*)d_in[2];
  const float* Wv    = (const float*)d_in[3];
  const float* Wa    = (const float*)d_in[4];
  const float* Wb    = (const float*)d_in[5];
  const float* Wg    = (const float*)d_in[6];
  const float* Wo    = (const float*)d_in[7];
  const float* cwq   = (const float*)d_in[8];
  const float* cwk   = (const float*)d_in[9];
  const float* cwv   = (const float*)d_in[10];
  const float* A_log = (const float*)d_in[11];
  const float* dt_b  = (const float*)d_in[12];
  const float* nw    = (const float*)d_in[13];
  float* out = (float*)d_out;

  char* wsb = (char*)d_ws;
  size_t off = 0;
  auto alloc = [&](size_t bytes)->char* {
    char* p = wsb + off; off += (bytes + 255) & ~(size_t)255; return p;
  };
  u16* WT   = (u16*)alloc((size_t)HID*VD*2);
  u16* bufA = (u16*)alloc((size_t)MROWS*VD*2);
  u16* bufB = (u16*)alloc((size_t)MROWS*VD*2);
  u16* bufC = (u16*)alloc((size_t)MROWS*VD*2);
  float2* gb = (float2*)alloc((size_t)MROWS*NH*8 + 4096);

  u16* q_lin = bufA;
  u16* k_lin = bufA + (size_t)MROWS*KD;
  u16* v_lin = bufB;
  u16* qc    = bufC;
  u16* kc    = bufC + (size_t)MROWS*KD;
  u16* vcp   = bufA;          // after q/k convs consume q_lin/k_lin
  u16* op    = bufB;          // after v conv consumes v_lin
  u16* gatep = bufC;          // after scan consumes qc/kc
  u16* yp    = bufA;          // after scan consumes vcp

  dim3 blk256(256);

  // q projection
  transpose_f2b<<<dim3(KD/64, HID/64), blk256, 0, stream>>>(Wq, WT, HID, KD);
  gemm_f32a_bt<<<dim3(KD/128, MROWS/128), blk256, 0, stream>>>(hs, WT, q_lin, MROWS, KD, HID);
  // k projection
  transpose_f2b<<<dim3(KD/64, HID/64), blk256, 0, stream>>>(Wk, WT, HID, KD);
  gemm_f32a_bt<<<dim3(KD/128, MROWS/128), blk256, 0, stream>>>(hs, WT, k_lin, MROWS, KD, HID);
  // v projection
  transpose_f2b<<<dim3(VD/64, HID/64), blk256, 0, stream>>>(Wv, WT, HID, VD);
  gemm_f32a_bt<<<dim3(VD/128, MROWS/128), blk256, 0, stream>>>(hs, WT, v_lin, MROWS, VD, HID);
  // a/b projections + activations -> {exp(g), beta}
  proj_ab<<<dim3(MROWS), dim3(64), 0, stream>>>(hs, Wa, Wb, A_log, dt_b, gb);

  // convs (+ l2norm for q/k; q also * dk^-0.5). q,k before v (vcp overwrites bufA).
  conv_norm_qk<<<dim3(MROWS, NH), blk256, 0, stream>>>(q_lin, cwq, qc, 0.0625f);
  conv_norm_qk<<<dim3(MROWS, NH), blk256, 0, stream>>>(k_lin, cwk, kc, 1.0f);
  conv_v_k<<<dim3(MROWS), dim3(384), 0, stream>>>(v_lin, cwv, vcp);

  // gated delta rule scan v4 -> op (bf16, overwrites v_lin region)
  scan_k4<<<dim3(DV/4, NH, B_), dim3(64), 0, stream>>>(qc, kc, vcp, gb, op);

  // gate projection (into bufC, now free)
  transpose_f2b<<<dim3(VD/64, HID/64), blk256, 0, stream>>>(Wg, WT, HID, VD);
  gemm_f32a_bt<<<dim3(VD/128, MROWS/128), blk256, 0, stream>>>(hs, WT, gatep, MROWS, VD, HID);

  // RMSNorm * nw * silu(gate) -> y (into bufA, now free)
  norm_gate_k<<<dim3(MROWS, NH), blk256, 0, stream>>>(op, gatep, nw, yp);

  // output projection: out(f32) = y @ Wo  (Wo [VD][HID] -> WoT [HID][VD])
  transpose_f2b<<<dim3(HID/64, VD/64), blk256, 0, stream>>>(Wo, WT, VD, HID);
  gemm_bt_f32out<<<dim3(HID/128, MROWS/128), blk256, 0, stream>>>(yp, WT, out, MROWS, HID, VD);
}